// Round 3
// baseline (1564.494 us; speedup 1.0000x reference)
//
#include <hip/hip_runtime.h>
#include <math.h>

#define Bb 2
#define Hh 8
#define Ss 512
#define Dd 64

typedef float floatx4 __attribute__((ext_vector_type(4)));

// One wave = one q-row. Phase 1: 4 lanes per k (quad owns a 256 B k-row),
// 16 k / 4 KiB per iteration, 2-step shuffle reduce. Phase 2: wave-local
// softmax. Phase 3: p broadcast via ds_read_b128, float4 V accumulate.
__global__ __launch_bounds__(256) void relattn_kernel(
    const float* __restrict__ Q, const float* __restrict__ Kmat,
    const float* __restrict__ V, const float* __restrict__ R,
    const int* __restrict__ mask, float* __restrict__ out,
    float* __restrict__ p_out)
{
    __shared__ float ssc_all[4][Ss];          // 8 KB: per-wave score buffer

    const int tid  = threadIdx.x;
    const int wave = tid >> 6;
    const int lane = tid & 63;
    float* ssc = ssc_all[wave];

    const int row = blockIdx.x * 4 + wave;    // [0, B*H*S)
    const int q   = row & (Ss - 1);
    const int bh  = row >> 9;                 // b*H + h
    const int b   = bh >> 3;                  // H == 8

    const float* Rrow = R    + (size_t)row * Ss * Dd;
    const float* Kbh  = Kmat + (size_t)bh  * Ss * Dd;
    const float* Vbh  = V    + (size_t)bh  * Ss * Dd;

    // ---- Phase 1: scores[k] = (q . (K_k + R_qk)) / 8 ----
    const int j4 = lane & 3;                  // quad-lane: d = j4*16 .. j4*16+15
    const int kk = lane >> 2;                 // 16 k per iteration

    const float* Qrow = Q + (size_t)row * Dd + j4 * 16;
    const floatx4 qf0 = *(const floatx4*)(Qrow + 0);
    const floatx4 qf1 = *(const floatx4*)(Qrow + 4);
    const floatx4 qf2 = *(const floatx4*)(Qrow + 8);
    const floatx4 qf3 = *(const floatx4*)(Qrow + 12);

    #pragma unroll 2
    for (int i = 0; i < Ss / 16; ++i) {
        const int k = i * 16 + kk;
        const float* rp = Rrow + k * Dd + j4 * 16;
        const float* kp = Kbh  + k * Dd + j4 * 16;
        floatx4 r0 = __builtin_nontemporal_load((const floatx4*)(rp + 0));
        floatx4 r1 = __builtin_nontemporal_load((const floatx4*)(rp + 4));
        floatx4 r2 = __builtin_nontemporal_load((const floatx4*)(rp + 8));
        floatx4 r3 = __builtin_nontemporal_load((const floatx4*)(rp + 12));
        floatx4 k0 = *(const floatx4*)(kp + 0);
        floatx4 k1 = *(const floatx4*)(kp + 4);
        floatx4 k2 = *(const floatx4*)(kp + 8);
        floatx4 k3 = *(const floatx4*)(kp + 12);
        float p;
        p  = qf0.x * (r0.x + k0.x) + qf0.y * (r0.y + k0.y)
           + qf0.z * (r0.z + k0.z) + qf0.w * (r0.w + k0.w);
        p += qf1.x * (r1.x + k1.x) + qf1.y * (r1.y + k1.y)
           + qf1.z * (r1.z + k1.z) + qf1.w * (r1.w + k1.w);
        p += qf2.x * (r2.x + k2.x) + qf2.y * (r2.y + k2.y)
           + qf2.z * (r2.z + k2.z) + qf2.w * (r2.w + k2.w);
        p += qf3.x * (r3.x + k3.x) + qf3.y * (r3.y + k3.y)
           + qf3.z * (r3.z + k3.z) + qf3.w * (r3.w + k3.w);
        p += __shfl_xor(p, 1);                // 2-step quad reduce
        p += __shfl_xor(p, 2);
        if (j4 == 0) ssc[k] = p * 0.125f;     // 16 lanes, 16 distinct banks
    }
    __builtin_amdgcn_wave_barrier();

    // ---- Phase 2: wave-local masked softmax; lane owns k = lane + 64*i ----
    const int* mrow = mask + (size_t)(b * Ss + q) * Ss;
    float s[8]; int m[8];
    #pragma unroll
    for (int i = 0; i < 8; ++i) {
        m[i] = mrow[lane + 64 * i];
        s[i] = ssc[lane + 64 * i];            // 2-way bank alias: free
        if (m[i] == 0) s[i] = -1e9f;
    }
    float mx = s[0];
    #pragma unroll
    for (int i = 1; i < 8; ++i) mx = fmaxf(mx, s[i]);
    #pragma unroll
    for (int o = 1; o < 64; o <<= 1) mx = fmaxf(mx, __shfl_xor(mx, o));

    float e[8], sm = 0.0f;
    #pragma unroll
    for (int i = 0; i < 8; ++i) { e[i] = __expf(s[i] - mx); sm += e[i]; }
    #pragma unroll
    for (int o = 1; o < 64; o <<= 1) sm += __shfl_xor(sm, o);
    const float inv = 1.0f / sm;

    float* prow = p_out + (size_t)row * Ss;
    #pragma unroll
    for (int i = 0; i < 8; ++i) {
        float p = (m[i] == 0) ? 0.0f : e[i] * inv;
        prow[lane + 64 * i] = p;              // coalesced 256 B stores
        ssc[lane + 64 * i]  = p;
    }
    __builtin_amdgcn_wave_barrier();

    // ---- Phase 3: out[row][:] = p . V ----
    const int j16 = lane & 15;                // d = j16*4 .. j16*4+3
    const int kg  = lane >> 4;                // 4 k-groups
    floatx4 acc = {0.f, 0.f, 0.f, 0.f};
    #pragma unroll 2
    for (int i = 0; i < Ss / 16; ++i) {
        const int kb = i * 16 + kg * 4;       // group's 4 consecutive k
        floatx4 pv = *(const floatx4*)&ssc[kb];   // 1 ds_read_b128 per 4 k
        const float* vp = Vbh + (size_t)kb * Dd + j16 * 4;
        floatx4 v0 = *(const floatx4*)(vp + 0 * Dd);
        floatx4 v1 = *(const floatx4*)(vp + 1 * Dd);
        floatx4 v2 = *(const floatx4*)(vp + 2 * Dd);
        floatx4 v3 = *(const floatx4*)(vp + 3 * Dd);
        acc.x = fmaf(pv.x, v0.x, acc.x); acc.y = fmaf(pv.x, v0.y, acc.y);
        acc.z = fmaf(pv.x, v0.z, acc.z); acc.w = fmaf(pv.x, v0.w, acc.w);
        acc.x = fmaf(pv.y, v1.x, acc.x); acc.y = fmaf(pv.y, v1.y, acc.y);
        acc.z = fmaf(pv.y, v1.z, acc.z); acc.w = fmaf(pv.y, v1.w, acc.w);
        acc.x = fmaf(pv.z, v2.x, acc.x); acc.y = fmaf(pv.z, v2.y, acc.y);
        acc.z = fmaf(pv.z, v2.z, acc.z); acc.w = fmaf(pv.z, v2.w, acc.w);
        acc.x = fmaf(pv.w, v3.x, acc.x); acc.y = fmaf(pv.w, v3.y, acc.y);
        acc.z = fmaf(pv.w, v3.z, acc.z); acc.w = fmaf(pv.w, v3.w, acc.w);
    }
    // reduce across the 4 k-groups (lanes xor 16, 32)
    #pragma unroll
    for (int o = 16; o <= 32; o <<= 1) {
        acc.x += __shfl_xor(acc.x, o);
        acc.y += __shfl_xor(acc.y, o);
        acc.z += __shfl_xor(acc.z, o);
        acc.w += __shfl_xor(acc.w, o);
    }
    if (kg == 0)
        *(floatx4*)(out + (size_t)row * Dd + j16 * 4) = acc;
}

extern "C" void kernel_launch(void* const* d_in, const int* in_sizes, int n_in,
                              void* d_out, int out_size, void* d_ws, size_t ws_size,
                              hipStream_t stream) {
    const float* Q    = (const float*)d_in[0];
    const float* K    = (const float*)d_in[1];
    const float* V    = (const float*)d_in[2];
    const float* R    = (const float*)d_in[3];
    const int*   mask = (const int*)d_in[4];

    float* out   = (float*)d_out;
    float* p_out = out + (size_t)Bb * Hh * Ss * Dd;   // tuple order: out, p_attn

    relattn_kernel<<<(Bb * Hh * Ss) / 4, 256, 0, stream>>>(Q, K, V, R, mask, out, p_out);
}